// Round 10
// baseline (67.204 us; speedup 1.0000x reference)
//
#include <hip/hip_runtime.h>

// ---------------------------------------------------------------------------
// LIIF forward, MI355X — layer-pass structure (r10).
//   k_prepw  : 34 blocks — weight repack to 16x16x32-MFMA fragment layouts
//   k_stage1 : fused transpose+conv (16x16x32 MFMA) -> P           [proven r7]
//   k_mlp0   : h0 build (P gather + rel terms) -> LDS -> GEMM w1 -> h
//   k_mlpL   : generic hidden layer: h -> LDS -> GEMM wL -> h (in place) x2
//   k_mlp4   : final 64ch GEMM + area-weighted corner combine -> out
// Rationale (r8/r9 counters): monolithic stage2 was latency-bound re-streaming
// 112 KB of weights PER WAVE from L2 (229-459 MB grid-wide, MfmaUtil 8%).
// Layer passes load weights once per 128-row block: 58 MB total, short chains.
// All LDS/MFMA mechanics are verbatim from passing kernels (stage1, r1, r9).
// LDS weight staging (DMA/ds_write >=64KB) remains condemned (r3/r5/r6).
// ---------------------------------------------------------------------------

typedef unsigned short U16;
typedef unsigned int   u32;
using f16x8  = __attribute__((ext_vector_type(8)))  _Float16;
using f32x4  = __attribute__((ext_vector_type(4)))  float;
using u16x8  = __attribute__((ext_vector_type(8)))  U16;
using u16x4  = __attribute__((ext_vector_type(4)))  U16;

// ws layout (f16 element offsets)
#define H_OFF    0          // 65536 rows x 128 = 8,388,608  (row = gq*4 + corner)
#define P_OFF    8388608    // 2*16384*128     = 4,194,304
#define W0F_OFF  12582912   // 73,728  stage1 A-frags: [kpos][ks][mtile][lane][8]
#define W1G_OFF  12656640   // 3*16384 MLP A-frags:    [L][ks][mt][lane][8]
#define W4G_OFF  12705792   // 8,192   final A-frags:  [ks][mt4][lane][8]

__device__ __forceinline__ float h2f(U16 u){ _Float16 h; __builtin_memcpy(&h,&u,2); return (float)h; }
__device__ __forceinline__ U16 f2h(float f){ _Float16 h = (_Float16)f; U16 u; __builtin_memcpy(&u,&h,2); return u; }

__device__ __forceinline__ int nearest_idx(float g){
  float t = (g + 1.0f) * 128.0f;   // exact
  t = (t - 1.0f) * 0.5f;           // exact
  float r = rintf(t);              // half-even == np.round
  r = fminf(fmaxf(r, 0.0f), 127.0f);
  return (int)r;
}
__device__ __forceinline__ float seqv(int i){ return -0.9921875f + 0.015625f*(float)i; }

// corner: 0:(-1,-1) 1:(-1,+1) 2:(+1,-1) 3:(+1,+1)
__device__ __forceinline__ void corner_calc(float c0, float c1, int corner,
                                            int& iy, int& ix, float& rel0, float& rel1){
  const float rx = 0.0078125f;
  float sx = (corner & 2) ? rx : -rx;
  float sy = (corner & 1) ? rx : -rx;
  float a0 = c0 + sx; a0 = a0 + 1e-6f; a0 = fminf(fmaxf(a0, -1.0f + 1e-6f), 1.0f - 1e-6f);
  float a1 = c1 + sy; a1 = a1 + 1e-6f; a1 = fminf(fmaxf(a1, -1.0f + 1e-6f), 1.0f - 1e-6f);
  iy = nearest_idx(a0);
  ix = nearest_idx(a1);
  rel0 = (c0 - seqv(ix)) * 128.0f;   // ref quirk: rel0 uses seq[ix]
  rel1 = (c1 - seqv(iy)) * 128.0f;
}

// ---------------------------------------------------------------------------
// k_prepw: 34 blocks (verbatim r9, new destination offsets).
__global__ __launch_bounds__(256) void k_prepw(
    const float* __restrict__ w0, const float* __restrict__ w1,
    const float* __restrict__ w2, const float* __restrict__ w3,
    const float* __restrict__ w4, U16* __restrict__ ws)
{
  __shared__ U16 sh[64 * 72];
  const int tid = threadIdx.x, bid = blockIdx.x;

  if (bid < 12) {
    int L = bid >> 2, ks = bid & 3;
    const float* src = (L == 0) ? w1 : (L == 1) ? w2 : w3;
    {
      int kl = tid >> 3, m0 = (tid & 7) << 4;
      const float* p = src + (((ks << 5) + kl) << 7) + m0;
      #pragma unroll
      for (int j = 0; j < 4; ++j) {
        float4 v = *(const float4*)(p + (j << 2));
        U16* d = &sh[(kl << 7) + m0 + (j << 2)];
        d[0]=f2h(v.x); d[1]=f2h(v.y); d[2]=f2h(v.z); d[3]=f2h(v.w);
      }
    }
    __syncthreads();
    {
      int lane = tid & 63, mtb = tid >> 6;
      #pragma unroll
      for (int i = 0; i < 2; ++i) {
        int mt = mtb + (i << 2);
        u16x8 o;
        #pragma unroll
        for (int e = 0; e < 8; ++e)
          o[e] = sh[((((lane >> 4) << 3) + e) << 7) + (mt << 4) + (lane & 15)];
        *(u16x8*)(ws + W1G_OFF + (L << 14) + (((ks << 3) + mt) << 9) + (lane << 3)) = o;
      }
    }
  } else if (bid < 16) {
    int ks = bid - 12;
    {
      int kl = tid >> 3, m0 = (tid & 7) << 3;
      const float* p = w4 + (((ks << 5) + kl) << 6) + m0;
      float4 a = *(const float4*)p, b2 = *(const float4*)(p + 4);
      U16* d = &sh[(kl << 6) + m0];
      d[0]=f2h(a.x); d[1]=f2h(a.y); d[2]=f2h(a.z); d[3]=f2h(a.w);
      d[4]=f2h(b2.x); d[5]=f2h(b2.y); d[6]=f2h(b2.z); d[7]=f2h(b2.w);
    }
    __syncthreads();
    {
      int lane = tid & 63, mt4 = tid >> 6;
      u16x8 o;
      #pragma unroll
      for (int e = 0; e < 8; ++e)
        o[e] = sh[((((lane >> 4) << 3) + e) << 6) + (mt4 << 4) + (lane & 15)];
      *(u16x8*)(ws + W4G_OFF + (((ks << 2) + mt4) << 9) + (lane << 3)) = o;
    }
  } else {
    int t2 = bid - 16, kpos = t2 >> 1, ks = t2 & 1;
    {
      int cc = tid >> 3, o0 = (tid & 7) << 4;
      const float* p = w0 + ((size_t)((((ks << 5) + cc) * 9) + kpos) << 7) + o0;
      #pragma unroll
      for (int j = 0; j < 4; ++j) {
        float4 v = *(const float4*)(p + (j << 2));
        U16* d = &sh[(cc << 7) + o0 + (j << 2)];
        d[0]=f2h(v.x); d[1]=f2h(v.y); d[2]=f2h(v.z); d[3]=f2h(v.w);
      }
    }
    __syncthreads();
    {
      int lane = tid & 63, mt0 = tid >> 6;
      #pragma unroll
      for (int i = 0; i < 2; ++i) {
        int mtile = mt0 + (i << 2);
        u16x8 o;
        #pragma unroll
        for (int e = 0; e < 8; ++e)
          o[e] = sh[((((lane >> 4) << 3) + e) << 7) + (mtile << 4) + (lane & 15)];
        *(u16x8*)(ws + W0F_OFF + (((((kpos << 1) + ks) << 3) + mtile) << 9) + (lane << 3)) = o;
      }
    }
  }
}

// ---------------------------------------------------------------------------
// Stage 1 (fused transpose+conv): verbatim r7 (passing).
__global__ __launch_bounds__(256) void k_stage1(const float* __restrict__ x,
                                                const U16* __restrict__ w0f,
                                                const float* __restrict__ b0,
                                                U16* __restrict__ P)
{
  __shared__ U16 araw[3 * 66 * 64];
  const int tid = threadIdx.x, bid = blockIdx.x;
  const int b = bid >> 8, rem = bid & 255;
  const int y = rem >> 1, x0 = (rem & 1) << 6;

  {
    int c = tid & 63, dy = tid >> 6;
    if (dy < 3) {
      int yy = y + dy - 1;
      bool rowok = (yy >= 0) && (yy < 128);
      const float* xr = rowok
        ? (x + ((((size_t)b << 6) + c) << 14) + ((size_t)yy << 7)) : x;
      U16* arow = &araw[(dy * 66) * 64];
      {
        float v0 = 0.0f, v65 = 0.0f;
        if (rowok && x0 > 0)        v0  = xr[x0 - 1];
        if (rowok && x0 + 64 < 128) v65 = xr[x0 + 64];
        arow[0 * 64 + c] = f2h(v0);
        arow[65 * 64 + (c ^ 8)] = f2h(v65);
      }
      if (rowok) {
        #pragma unroll
        for (int g = 0; g < 16; ++g) {
          float4 v = *(const float4*)(xr + x0 + (g << 2));
          #pragma unroll
          for (int j = 0; j < 4; ++j) {
            int xp = 1 + (g << 2) + j;
            float vj = (j == 0) ? v.x : (j == 1) ? v.y : (j == 2) ? v.z : v.w;
            arow[xp * 64 + (c ^ ((xp & 7) << 3))] = f2h(vj);
          }
        }
      } else {
        #pragma unroll
        for (int xp = 1; xp <= 64; ++xp)
          arow[xp * 64 + (c ^ ((xp & 7) << 3))] = f2h(0.0f);
      }
    }
  }
  __syncthreads();

  const int wv = tid >> 6, ln = tid & 63;
  const int lrow = ln & 15, lg = ln >> 4;

  f32x4 acc[2][4];
  #pragma unroll
  for (int m = 0; m < 2; ++m)
    #pragma unroll
    for (int n = 0; n < 4; ++n) acc[m][n] = (f32x4){0.f, 0.f, 0.f, 0.f};

  #pragma unroll
  for (int kpos = 0; kpos < 9; ++kpos) {
    const int dyr = kpos / 3;
    const int dx = kpos % 3 - 1;
    f16x8 a[2][2];
    #pragma unroll
    for (int mf = 0; mf < 2; ++mf)
      #pragma unroll
      for (int ks = 0; ks < 2; ++ks) {
        size_t off = ((size_t)((((kpos << 1) + ks) << 3) + ((wv << 1) + mf)) << 9) + (ln << 3);
        a[mf][ks] = *(const f16x8*)(w0f + off);
      }
    #pragma unroll
    for (int ks = 0; ks < 2; ++ks)
      #pragma unroll
      for (int nf = 0; nf < 4; ++nf) {
        int xp = (nf << 4) + lrow + dx + 1;
        int cc = ((ks << 5) + (lg << 3)) ^ ((xp & 7) << 3);
        f16x8 bf = *(const f16x8*)(&araw[(dyr * 66 + xp) * 64 + cc]);
        acc[0][nf] = __builtin_amdgcn_mfma_f32_16x16x32_f16(a[0][ks], bf, acc[0][nf], 0, 0, 0);
        acc[1][nf] = __builtin_amdgcn_mfma_f32_16x16x32_f16(a[1][ks], bf, acc[1][nf], 0, 0, 0);
      }
  }

  #pragma unroll
  for (int mf = 0; mf < 2; ++mf) {
    int o0 = (wv << 5) + (mf << 4) + (lg << 2);
    float bb[4];
    #pragma unroll
    for (int r = 0; r < 4; ++r) bb[r] = b0[o0 + r];
    #pragma unroll
    for (int nf = 0; nf < 4; ++nf) {
      int px = x0 + (nf << 4) + lrow;
      u16x4 w;
      #pragma unroll
      for (int r = 0; r < 4; ++r) w[r] = f2h(acc[mf][nf][r] + bb[r]);
      *(u16x4*)(P + ((size_t)((b << 14) + (y << 7) + px)) * 128 + o0) = w;
    }
  }
}

// ---------------------------------------------------------------------------
// Shared GEMM core for MLP layers: actT (swizzled) x wg -> relu -> h rows.
// Wave wv covers m-tiles {2wv, 2wv+1}; 8 nf row-frags; 4 ks.
__device__ __forceinline__ void mlp_gemm_write(
    const U16* actT, const U16* __restrict__ wg, const float* __restrict__ bL,
    U16* __restrict__ h, int r0, int tid)
{
  const int wv = tid >> 6, ln = tid & 63;
  const int lrow = ln & 15, lg = ln >> 4;

  f32x4 acc[2][8];
  #pragma unroll
  for (int mt = 0; mt < 2; ++mt) {
    int o0 = (((wv << 1) + mt) << 4) + (lg << 2);
    f32x4 bv = *(const f32x4*)(bL + o0);
    #pragma unroll
    for (int nf = 0; nf < 8; ++nf) acc[mt][nf] = bv;
  }
  #pragma unroll
  for (int ks = 0; ks < 4; ++ks) {
    f16x8 a[2];
    #pragma unroll
    for (int mt = 0; mt < 2; ++mt)
      a[mt] = *(const f16x8*)(wg + (((ks << 3) + (wv << 1) + mt) << 9) + (ln << 3));
    #pragma unroll
    for (int nf = 0; nf < 8; ++nf) {
      int rr = (nf << 4) + lrow;
      int kk = ((ks << 5) + (lg << 3)) ^ ((rr & 7) << 3);
      f16x8 bf = *(const f16x8*)(&actT[(rr << 7) + kk]);
      acc[0][nf] = __builtin_amdgcn_mfma_f32_16x16x32_f16(a[0], bf, acc[0][nf], 0, 0, 0);
      acc[1][nf] = __builtin_amdgcn_mfma_f32_16x16x32_f16(a[1], bf, acc[1][nf], 0, 0, 0);
    }
  }
  #pragma unroll
  for (int mt = 0; mt < 2; ++mt) {
    int o0 = (((wv << 1) + mt) << 4) + (lg << 2);
    #pragma unroll
    for (int nf = 0; nf < 8; ++nf) {
      int row = r0 + (nf << 4) + lrow;
      u16x4 w;
      #pragma unroll
      for (int r = 0; r < 4; ++r) w[r] = f2h(fmaxf(acc[mt][nf][r], 0.0f));
      *(u16x4*)(h + ((size_t)row << 7) + o0) = w;
    }
  }
}

// ---------------------------------------------------------------------------
// k_mlp0: h0 build (P gather + rel terms) -> LDS, GEMM w1 -> h. 512 blocks.
__global__ __launch_bounds__(256, 2) void k_mlp0(
    const U16* __restrict__ P,
    const float* __restrict__ coord, const float* __restrict__ cell,
    const float* __restrict__ w0,
    const U16* __restrict__ w1g, const float* __restrict__ b1,
    U16* __restrict__ h)
{
  __shared__ U16 actT[128 * 128];
  const int tid = threadIdx.x, bid = blockIdx.x;
  const int r0 = bid << 7;

  {
    int r = tid >> 1, hf = tid & 1;
    int rr = r0 + r;
    int gq = rr >> 2, cc = rr & 3, bimg = gq >> 13;
    float c0v = coord[gq * 2 + 0], c1v = coord[gq * 2 + 1];
    float rc0 = cell[gq * 2 + 0] * 128.0f, rc1 = cell[gq * 2 + 1] * 128.0f;
    int iy, ix; float rel0, rel1;
    corner_calc(c0v, c1v, cc, iy, ix, rel0, rel1);
    int lin = iy * 128 + ix;
    const U16* Pr = P + (((size_t)(bimg << 14) + lin) << 7);
    const float* tu = w0 + 576 * 128;
    const float* tv = tu + 128;
    const float* ts2 = tv + 128;
    const float* tt = ts2 + 128;
    #pragma unroll
    for (int j = 0; j < 8; ++j) {
      int n0 = (hf << 6) + (j << 3);
      u16x8 pv = *(const u16x8*)(Pr + n0);
      f32x4 ua = *(const f32x4*)(tu + n0),  ub = *(const f32x4*)(tu + n0 + 4);
      f32x4 va = *(const f32x4*)(tv + n0),  vb = *(const f32x4*)(tv + n0 + 4);
      f32x4 sa = *(const f32x4*)(ts2 + n0), sb = *(const f32x4*)(ts2 + n0 + 4);
      f32x4 ta = *(const f32x4*)(tt + n0),  tb = *(const f32x4*)(tt + n0 + 4);
      u16x8 res;
      #pragma unroll
      for (int e = 0; e < 8; ++e) {
        float uu  = (e < 4) ? ua[e & 3] : ub[e & 3];
        float vvv = (e < 4) ? va[e & 3] : vb[e & 3];
        float ss  = (e < 4) ? sa[e & 3] : sb[e & 3];
        float t2  = (e < 4) ? ta[e & 3] : tb[e & 3];
        float hh = h2f(pv[e]) + rel0 * uu + rel1 * vvv + rc0 * ss + rc1 * t2;
        res[e] = f2h(fmaxf(hh, 0.0f));
      }
      *(u16x8*)(&actT[(r << 7) + (n0 ^ ((r & 7) << 3))]) = res;
    }
  }
  __syncthreads();
  mlp_gemm_write(actT, w1g, b1, h, r0, tid);
}

// ---------------------------------------------------------------------------
// k_mlpL: generic hidden layer, in place on h. 512 blocks.
__global__ __launch_bounds__(256, 2) void k_mlpL(
    const U16* __restrict__ wg, const float* __restrict__ bL,
    U16* __restrict__ h)
{
  __shared__ U16 actT[128 * 128];
  const int tid = threadIdx.x, bid = blockIdx.x;
  const int r0 = bid << 7;

  #pragma unroll
  for (int i = 0; i < 8; ++i) {
    int u = tid + (i << 8);
    int r = u >> 4, seg = u & 15;
    u16x8 v = *(const u16x8*)(h + ((size_t)(r0 + r) << 7) + (seg << 3));
    *(u16x8*)(&actT[(r << 7) + ((seg << 3) ^ ((r & 7) << 3))]) = v;
  }
  __syncthreads();
  mlp_gemm_write(actT, wg, bL, h, r0, tid);
}

// ---------------------------------------------------------------------------
// k_mlp4: final 128->64 + area-weighted corner combine. 512 blocks.
// Wave wv covers rows [32wv, 32wv+32) (2 nf), all 4 m-tiles (64 outch).
__global__ __launch_bounds__(256, 2) void k_mlp4(
    const U16* __restrict__ w4g, const float* __restrict__ b4,
    const float* __restrict__ coord, const float* __restrict__ cell,
    const U16* __restrict__ h, float* __restrict__ out)
{
  __shared__ U16 actT[128 * 128];
  const int tid = threadIdx.x, bid = blockIdx.x;
  const int r0 = bid << 7;

  #pragma unroll
  for (int i = 0; i < 8; ++i) {
    int u = tid + (i << 8);
    int r = u >> 4, seg = u & 15;
    u16x8 v = *(const u16x8*)(h + ((size_t)(r0 + r) << 7) + (seg << 3));
    *(u16x8*)(&actT[(r << 7) + ((seg << 3) ^ ((r & 7) << 3))]) = v;
  }
  __syncthreads();

  const int wv = tid >> 6, ln = tid & 63;
  const int lrow = ln & 15, lg = ln >> 4;

  f32x4 acc[4][2];
  #pragma unroll
  for (int mt4 = 0; mt4 < 4; ++mt4)
    #pragma unroll
    for (int nfl = 0; nfl < 2; ++nfl) acc[mt4][nfl] = (f32x4){0.f, 0.f, 0.f, 0.f};

  #pragma unroll
  for (int ks = 0; ks < 4; ++ks) {
    f16x8 a[4];
    #pragma unroll
    for (int mt4 = 0; mt4 < 4; ++mt4)
      a[mt4] = *(const f16x8*)(w4g + (((ks << 2) + mt4) << 9) + (ln << 3));
    #pragma unroll
    for (int nfl = 0; nfl < 2; ++nfl) {
      int rr = (wv << 5) + (nfl << 4) + lrow;
      int kk = ((ks << 5) + (lg << 3)) ^ ((rr & 7) << 3);
      f16x8 bf = *(const f16x8*)(&actT[(rr << 7) + kk]);
      #pragma unroll
      for (int mt4 = 0; mt4 < 4; ++mt4)
        acc[mt4][nfl] = __builtin_amdgcn_mfma_f32_16x16x32_f16(a[mt4], bf, acc[mt4][nfl], 0, 0, 0);
    }
  }

  #pragma unroll
  for (int nfl = 0; nfl < 2; ++nfl) {
    int rl = (wv << 5) + (nfl << 4) + lrow;
    int rglob = r0 + rl;
    int gq = rglob >> 2, cc = rl & 3;
    float c0v = coord[gq * 2 + 0], c1v = coord[gq * 2 + 1];
    float area[4];
    #pragma unroll
    for (int c4 = 0; c4 < 4; ++c4) {
      int iy, ix; float rr0, rr1;
      corner_calc(c0v, c1v, c4, iy, ix, rr0, rr1);
      area[c4] = fabsf(rr0 * rr1) + 1e-9f;
    }
    float tot = ((area[0] + area[1]) + area[2]) + area[3];
    float wgt = area[3 - cc] / tot;        // perm = (3,2,1,0)
    float tacc[4][4];
    #pragma unroll
    for (int mt4 = 0; mt4 < 4; ++mt4)
      #pragma unroll
      for (int r = 0; r < 4; ++r) {
        float v = acc[mt4][nfl][r] * wgt;
        v += __shfl_xor(v, 1, 64);
        v += __shfl_xor(v, 2, 64);
        tacc[mt4][r] = v;
      }
    if (cc == 0) {
      #pragma unroll
      for (int mt4 = 0; mt4 < 4; ++mt4) {
        int mo = (mt4 << 4) + (lg << 2);
        f32x4 bv = *(const f32x4*)(b4 + mo);
        f32x4 res;
        #pragma unroll
        for (int r = 0; r < 4; ++r) res[r] = tacc[mt4][r] + bv[r];
        *(f32x4*)(out + (size_t)gq * 64 + mo) = res;
      }
    }
  }
}

// ---------------------------------------------------------------------------
extern "C" void kernel_launch(void* const* d_in, const int* in_sizes, int n_in,
                              void* d_out, int out_size, void* d_ws, size_t ws_size,
                              hipStream_t stream)
{
  const float* x     = (const float*)d_in[0];
  const float* coord = (const float*)d_in[1];
  const float* cell  = (const float*)d_in[2];
  const float* w0    = (const float*)d_in[3];
  const float* b0    = (const float*)d_in[4];
  const float* w1    = (const float*)d_in[5];
  const float* b1    = (const float*)d_in[6];
  const float* w2    = (const float*)d_in[7];
  const float* b2    = (const float*)d_in[8];
  const float* w3    = (const float*)d_in[9];
  const float* b3    = (const float*)d_in[10];
  const float* w4    = (const float*)d_in[11];
  const float* b4    = (const float*)d_in[12];
  U16* ws = (U16*)d_ws;

  hipLaunchKernelGGL(k_prepw,  dim3(34),  dim3(256), 0, stream, w0, w1, w2, w3, w4, ws);
  hipLaunchKernelGGL(k_stage1, dim3(512), dim3(256), 0, stream,
                     x, ws + W0F_OFF, b0, ws + P_OFF);
  hipLaunchKernelGGL(k_mlp0,   dim3(512), dim3(256), 0, stream,
                     ws + P_OFF, coord, cell, w0, ws + W1G_OFF, b1, ws + H_OFF);
  hipLaunchKernelGGL(k_mlpL,   dim3(512), dim3(256), 0, stream,
                     ws + W1G_OFF + 16384, b2, ws + H_OFF);
  hipLaunchKernelGGL(k_mlpL,   dim3(512), dim3(256), 0, stream,
                     ws + W1G_OFF + 32768, b3, ws + H_OFF);
  hipLaunchKernelGGL(k_mlp4,   dim3(512), dim3(256), 0, stream,
                     ws + W4G_OFF, b4, coord, cell, ws + H_OFF, (float*)d_out);
}

// Round 12
// 46.788 us; speedup vs baseline: 1.4363x; 1.4363x over previous
//
#include <hip/hip_runtime.h>

// ---------------------------------------------------------------------------
// LIIF forward, MI355X (r12 = r11 with macro-semicolon compile fix).
//   k_prepw  : 50 blocks — weight repack to 32x32-MFMA fragment streams
//   k_stage1 : fused transpose+conv (16x16x32 MFMA) -> P          [proven r7]
//   k_stage2 : in-register MLP, wave = 8 queries x 4 corners = 32 cols,
//              32x32x16 MFMA. A-frags 4-deep register double-buffered
//              (issue 4 steps ahead, sched_barrier-pinned) and per-layer
//              __syncthreads to phase-lock the block's waves for L1 reuse.
// r8 counters for old stage2: MfmaUtil 8%, VALU 20%, Occ 11% -> ~400cyc/load,
// zero overlap. This round: hide/dedupe the weight stream, same math.
// LDS weight staging (DMA/ds_write) remains condemned (r3/r5/r6).
// ---------------------------------------------------------------------------

typedef unsigned short U16;
typedef unsigned int   u32;
using f16x8  = __attribute__((ext_vector_type(8)))  _Float16;
using f32x4  = __attribute__((ext_vector_type(4)))  float;
using f32x16 = __attribute__((ext_vector_type(16))) float;
using u16x8  = __attribute__((ext_vector_type(8)))  U16;
using u16x4  = __attribute__((ext_vector_type(4)))  U16;

// ws layout (f16 element offsets)
#define P_OFF    2097152    // 2*16384*128  = 4,194,304
#define W0F_OFF  6291456    // 73,728  stage1 A-frags: [kpos][ks][mtile][lane][8]
#define W1F_OFF  6365184    // 3*16384 stage2 A-frags: [L][s][mt][lane][8]
#define W4F_OFF  6414336    // 8,192   stage2 final:   [s][mt4][lane][8]

__device__ __forceinline__ float h2f(U16 u){ _Float16 h; __builtin_memcpy(&h,&u,2); return (float)h; }
__device__ __forceinline__ U16 f2h(float f){ _Float16 h = (_Float16)f; U16 u; __builtin_memcpy(&u,&h,2); return u; }
__device__ __forceinline__ u32 packf16(float a, float b){
  _Float16 ha = (_Float16)a, hb = (_Float16)b;
  U16 ua, ub; __builtin_memcpy(&ua,&ha,2); __builtin_memcpy(&ub,&hb,2);
  return (u32)ua | ((u32)ub << 16);
}
__device__ __forceinline__ f16x8 bfrag(const u32* w){
  union { u32 u[4]; f16x8 v; } t;
  t.u[0]=w[0]; t.u[1]=w[1]; t.u[2]=w[2]; t.u[3]=w[3];
  return t.v;
}

__device__ __forceinline__ int nearest_idx(float g){
  float t = (g + 1.0f) * 128.0f;   // exact
  t = (t - 1.0f) * 0.5f;           // exact
  float r = rintf(t);              // half-even == np.round
  r = fminf(fmaxf(r, 0.0f), 127.0f);
  return (int)r;
}
__device__ __forceinline__ float seqv(int i){ return -0.9921875f + 0.015625f*(float)i; }

// corner: 0:(-1,-1) 1:(-1,+1) 2:(+1,-1) 3:(+1,+1)
__device__ __forceinline__ void corner_calc(float c0, float c1, int corner,
                                            int& iy, int& ix, float& rel0, float& rel1){
  const float rx = 0.0078125f;
  float sx = (corner & 2) ? rx : -rx;
  float sy = (corner & 1) ? rx : -rx;
  float a0 = c0 + sx; a0 = a0 + 1e-6f; a0 = fminf(fmaxf(a0, -1.0f + 1e-6f), 1.0f - 1e-6f);
  float a1 = c1 + sy; a1 = a1 + 1e-6f; a1 = fminf(fmaxf(a1, -1.0f + 1e-6f), 1.0f - 1e-6f);
  iy = nearest_idx(a0);
  ix = nearest_idx(a1);
  rel0 = (c0 - seqv(ix)) * 128.0f;   // ref quirk: rel0 uses seq[ix]
  rel1 = (c1 - seqv(iy)) * 128.0f;
}

// ---------------------------------------------------------------------------
// k_prepw: 50 blocks (r7 layouts: 32x32 frags for stage2, conv frags for s1).
__global__ __launch_bounds__(256) void k_prepw(
    const float* __restrict__ w0, const float* __restrict__ w1,
    const float* __restrict__ w2, const float* __restrict__ w3,
    const float* __restrict__ w4, U16* __restrict__ ws)
{
  __shared__ U16 sh[64 * 72];
  const int tid = threadIdx.x, bid = blockIdx.x;

  if (bid < 24) {
    // wLf[s][mt][lane][e] = wL[k*128+m], m=(mt<<5)+(lane&31), k=(s<<4)+((lane>>5)<<3)+e
    int L = bid >> 3, s = bid & 7;
    const float* src = (L == 0) ? w1 : (L == 1) ? w2 : w3;
    {
      int kk = tid >> 4, m0 = (tid & 15) << 3;
      const float* p = src + (((s << 4) + kk) << 7) + m0;
      float4 a = *(const float4*)p, b2v = *(const float4*)(p + 4);
      U16* d = &sh[kk * 128 + m0];
      d[0]=f2h(a.x); d[1]=f2h(a.y); d[2]=f2h(a.z); d[3]=f2h(a.w);
      d[4]=f2h(b2v.x); d[5]=f2h(b2v.y); d[6]=f2h(b2v.z); d[7]=f2h(b2v.w);
    }
    __syncthreads();
    {
      int mt = tid >> 6, lane = tid & 63;
      u16x8 o;
      #pragma unroll
      for (int e = 0; e < 8; ++e)
        o[e] = sh[((((lane >> 5) << 3) + e) << 7) + (mt << 5) + (lane & 31)];
      *(u16x8*)(ws + W1F_OFF + (L << 14) + (((s << 2) + mt) << 9) + (lane << 3)) = o;
    }
  } else if (bid < 32) {
    // w4f[s][mt4][lane][e] = w4[k*64+m], m=(mt4<<5)+(lane&31)
    int s = bid - 24;
    {
      int kk = tid >> 4, m0 = (tid & 15) << 2;
      float4 a = *(const float4*)(w4 + (((s << 4) + kk) << 6) + m0);
      U16* d = &sh[kk * 64 + m0];
      d[0]=f2h(a.x); d[1]=f2h(a.y); d[2]=f2h(a.z); d[3]=f2h(a.w);
    }
    __syncthreads();
    if (tid < 128) {
      int mt4 = tid >> 6, lane = tid & 63;
      u16x8 o;
      #pragma unroll
      for (int e = 0; e < 8; ++e)
        o[e] = sh[((((lane >> 5) << 3) + e) << 6) + (mt4 << 5) + (lane & 31)];
      *(u16x8*)(ws + W4F_OFF + (((s << 1) + mt4) << 9) + (lane << 3)) = o;
    }
  } else {
    // w0f[kpos][ks][mtile][lane][e] = w0[(c*9+kpos)*128+o]
    int t2 = bid - 32, kpos = t2 >> 1, ks = t2 & 1;
    {
      int cc = tid >> 3, o0 = (tid & 7) << 4;
      const float* p = w0 + ((size_t)((((ks << 5) + cc) * 9) + kpos) << 7) + o0;
      #pragma unroll
      for (int j = 0; j < 4; ++j) {
        float4 v = *(const float4*)(p + (j << 2));
        U16* d = &sh[(cc << 7) + o0 + (j << 2)];
        d[0]=f2h(v.x); d[1]=f2h(v.y); d[2]=f2h(v.z); d[3]=f2h(v.w);
      }
    }
    __syncthreads();
    {
      int lane = tid & 63, mt0 = tid >> 6;
      #pragma unroll
      for (int i = 0; i < 2; ++i) {
        int mtile = mt0 + (i << 2);
        u16x8 o;
        #pragma unroll
        for (int e = 0; e < 8; ++e)
          o[e] = sh[((((lane >> 4) << 3) + e) << 7) + (mtile << 4) + (lane & 15)];
        *(u16x8*)(ws + W0F_OFF + (((((kpos << 1) + ks) << 3) + mtile) << 9) + (lane << 3)) = o;
      }
    }
  }
}

// ---------------------------------------------------------------------------
// Stage 1 (fused transpose+conv): verbatim r7 (passing).
__global__ __launch_bounds__(256) void k_stage1(const float* __restrict__ x,
                                                const U16* __restrict__ w0f,
                                                const float* __restrict__ b0,
                                                U16* __restrict__ P)
{
  __shared__ U16 araw[3 * 66 * 64];
  const int tid = threadIdx.x, bid = blockIdx.x;
  const int b = bid >> 8, rem = bid & 255;
  const int y = rem >> 1, x0 = (rem & 1) << 6;

  {
    int c = tid & 63, dy = tid >> 6;
    if (dy < 3) {
      int yy = y + dy - 1;
      bool rowok = (yy >= 0) && (yy < 128);
      const float* xr = rowok
        ? (x + ((((size_t)b << 6) + c) << 14) + ((size_t)yy << 7)) : x;
      U16* arow = &araw[(dy * 66) * 64];
      {
        float v0 = 0.0f, v65 = 0.0f;
        if (rowok && x0 > 0)        v0  = xr[x0 - 1];
        if (rowok && x0 + 64 < 128) v65 = xr[x0 + 64];
        arow[0 * 64 + c] = f2h(v0);
        arow[65 * 64 + (c ^ 8)] = f2h(v65);
      }
      if (rowok) {
        #pragma unroll
        for (int g = 0; g < 16; ++g) {
          float4 v = *(const float4*)(xr + x0 + (g << 2));
          #pragma unroll
          for (int j = 0; j < 4; ++j) {
            int xp = 1 + (g << 2) + j;
            float vj = (j == 0) ? v.x : (j == 1) ? v.y : (j == 2) ? v.z : v.w;
            arow[xp * 64 + (c ^ ((xp & 7) << 3))] = f2h(vj);
          }
        }
      } else {
        #pragma unroll
        for (int xp = 1; xp <= 64; ++xp)
          arow[xp * 64 + (c ^ ((xp & 7) << 3))] = f2h(0.0f);
      }
    }
  }
  __syncthreads();

  const int wv = tid >> 6, ln = tid & 63;
  const int lrow = ln & 15, lg = ln >> 4;

  f32x4 acc[2][4];
  #pragma unroll
  for (int m = 0; m < 2; ++m)
    #pragma unroll
    for (int n = 0; n < 4; ++n) acc[m][n] = (f32x4){0.f, 0.f, 0.f, 0.f};

  #pragma unroll
  for (int kpos = 0; kpos < 9; ++kpos) {
    const int dyr = kpos / 3;
    const int dx = kpos % 3 - 1;
    f16x8 a[2][2];
    #pragma unroll
    for (int mf = 0; mf < 2; ++mf)
      #pragma unroll
      for (int ks = 0; ks < 2; ++ks) {
        size_t off = ((size_t)((((kpos << 1) + ks) << 3) + ((wv << 1) + mf)) << 9) + (ln << 3);
        a[mf][ks] = *(const f16x8*)(w0f + off);
      }
    #pragma unroll
    for (int ks = 0; ks < 2; ++ks)
      #pragma unroll
      for (int nf = 0; nf < 4; ++nf) {
        int xp = (nf << 4) + lrow + dx + 1;
        int cc = ((ks << 5) + (lg << 3)) ^ ((xp & 7) << 3);
        f16x8 bf = *(const f16x8*)(&araw[(dyr * 66 + xp) * 64 + cc]);
        acc[0][nf] = __builtin_amdgcn_mfma_f32_16x16x32_f16(a[0][ks], bf, acc[0][nf], 0, 0, 0);
        acc[1][nf] = __builtin_amdgcn_mfma_f32_16x16x32_f16(a[1][ks], bf, acc[1][nf], 0, 0, 0);
      }
  }

  #pragma unroll
  for (int mf = 0; mf < 2; ++mf) {
    int o0 = (wv << 5) + (mf << 4) + (lg << 2);
    float bb[4];
    #pragma unroll
    for (int r = 0; r < 4; ++r) bb[r] = b0[o0 + r];
    #pragma unroll
    for (int nf = 0; nf < 4; ++nf) {
      int px = x0 + (nf << 4) + lrow;
      u16x4 w;
      #pragma unroll
      for (int r = 0; r < 4; ++r) w[r] = f2h(acc[mf][nf][r] + bb[r]);
      *(u16x4*)(P + ((size_t)((b << 14) + (y << 7) + px)) * 128 + o0) = w;
    }
  }
}

// ---------------------------------------------------------------------------
// Stage 2: r7 math with pipelined A-frag loads + per-layer wave phase-lock.
#define LDA4(dst, base, sidx) \
  dst[0] = *(const f16x8*)((base) + ((((sidx) << 2) + 0) << 9) + lnoff); \
  dst[1] = *(const f16x8*)((base) + ((((sidx) << 2) + 1) << 9) + lnoff); \
  dst[2] = *(const f16x8*)((base) + ((((sidx) << 2) + 2) << 9) + lnoff); \
  dst[3] = *(const f16x8*)((base) + ((((sidx) << 2) + 3) << 9) + lnoff);
#define LDA2(dst, base, sidx) \
  dst[0] = *(const f16x8*)((base) + ((((sidx) << 1) + 0) << 9) + lnoff); \
  dst[1] = *(const f16x8*)((base) + ((((sidx) << 1) + 1) << 9) + lnoff);
#define HSTEP(s, AB, RF) do { \
  f16x8 Bv = bfrag(Bf[s]); \
  acc[0] = __builtin_amdgcn_mfma_f32_32x32x16_f16(AB[0], Bv, acc[0], 0, 0, 0); \
  acc[1] = __builtin_amdgcn_mfma_f32_32x32x16_f16(AB[1], Bv, acc[1], 0, 0, 0); \
  acc[2] = __builtin_amdgcn_mfma_f32_32x32x16_f16(AB[2], Bv, acc[2], 0, 0, 0); \
  acc[3] = __builtin_amdgcn_mfma_f32_32x32x16_f16(AB[3], Bv, acc[3], 0, 0, 0); \
  RF \
  __builtin_amdgcn_sched_barrier(0); \
} while (0)
#define FSTEP(s, AB, RF) do { \
  f16x8 Bv = bfrag(Bf[s]); \
  a4[0] = __builtin_amdgcn_mfma_f32_32x32x16_f16(AB[0], Bv, a4[0], 0, 0, 0); \
  a4[1] = __builtin_amdgcn_mfma_f32_32x32x16_f16(AB[1], Bv, a4[1], 0, 0, 0); \
  RF \
  __builtin_amdgcn_sched_barrier(0); \
} while (0)

__global__ __launch_bounds__(256) void k_stage2(
    const U16* __restrict__ P,
    const float* __restrict__ coord, const float* __restrict__ cell,
    const float* __restrict__ w0,
    const U16* __restrict__ w1f, const U16* __restrict__ w2f,
    const U16* __restrict__ w3f, const U16* __restrict__ w4f,
    const float* __restrict__ b1, const float* __restrict__ b2,
    const float* __restrict__ b3, const float* __restrict__ b4,
    float* __restrict__ out)
{
  const int tid = threadIdx.x;
  const int wv = tid >> 6, ln = tid & 63;
  const int wave = blockIdx.x * 4 + wv;
  const int q0 = wave << 3;
  const int col = ln & 31, h = ln >> 5;
  const int qi = col >> 2, c = col & 3;
  const int gq = q0 + qi;
  const int bimg = gq >> 13;
  const int lnoff = ln << 3;

  // ---- per-query corner math ----
  float c0v = coord[gq * 2 + 0], c1v = coord[gq * 2 + 1];
  float rc0 = cell[gq * 2 + 0] * 128.0f, rc1 = cell[gq * 2 + 1] * 128.0f;
  int lin4[4]; float r0v[4], r1v[4], area[4];
  #pragma unroll
  for (int c4 = 0; c4 < 4; ++c4) {
    int iy, ix; float r0, r1;
    corner_calc(c0v, c1v, c4, iy, ix, r0, r1);
    lin4[c4] = iy * 128 + ix;
    r0v[c4] = r0; r1v[c4] = r1;
    area[c4] = fabsf(r0 * r1) + 1e-9f;
  }
  float tot = ((area[0] + area[1]) + area[2]) + area[3];
  float wgt = area[3 - c] / tot;           // perm = (3,2,1,0)
  float rel0 = r0v[c], rel1 = r1v[c];

  // ---- P row prefetch (8 independent 16B loads) ----
  const U16* Pr = P + ((size_t)(bimg << 14) + lin4[c]) * 128;
  u16x8 pv[8];
  #pragma unroll
  for (int s = 0; s < 8; ++s)
    pv[s] = *(const u16x8*)(Pr + (s << 4) + (h << 3));

  // ---- issue layer-1 A batches 0..3 (16 loads fly during h0 build) ----
  f16x8 A0[4], A1[4], A2[4], A3[4];
  LDA4(A0, w1f, 0) LDA4(A1, w1f, 1) LDA4(A2, w1f, 2) LDA4(A3, w1f, 3)
  __builtin_amdgcn_sched_barrier(0);

  // ---- h0 -> Bf ----
  u32 Bf[8][4];
  {
    const float* tu = w0 + 576 * 128;
    const float* tv = tu + 128;
    const float* ts2 = tv + 128;
    const float* tt = ts2 + 128;
    #pragma unroll
    for (int s = 0; s < 8; ++s) {
      int k0 = (s << 4) + (h << 3);
      f32x4 ua = *(const f32x4*)(tu + k0),  ub = *(const f32x4*)(tu + k0 + 4);
      f32x4 va = *(const f32x4*)(tv + k0),  vb = *(const f32x4*)(tv + k0 + 4);
      f32x4 sa = *(const f32x4*)(ts2 + k0), sb = *(const f32x4*)(ts2 + k0 + 4);
      f32x4 ta = *(const f32x4*)(tt + k0),  tb = *(const f32x4*)(tt + k0 + 4);
      float hh[8];
      #pragma unroll
      for (int e = 0; e < 8; ++e) {
        float uu  = (e < 4) ? ua[e & 3] : ub[e & 3];
        float vvv = (e < 4) ? va[e & 3] : vb[e & 3];
        float ss  = (e < 4) ? sa[e & 3] : sb[e & 3];
        float t2  = (e < 4) ? ta[e & 3] : tb[e & 3];
        hh[e] = fmaxf(h2f(pv[s][e]) + rel0 * uu + rel1 * vvv + rc0 * ss + rc1 * t2, 0.0f);
      }
      #pragma unroll
      for (int w = 0; w < 4; ++w)
        Bf[s][w] = packf16(hh[2 * w], hh[2 * w + 1]);
    }
  }
  __syncthreads();   // phase-lock the block's 4 waves (L1 weight reuse)

  // ---- hidden layers 1..3 (pipelined A stream) ----
  const U16* wf_[3] = {w1f, w2f, w3f};
  const U16* wn_[3] = {w2f, w3f, w4f};
  const float* bL_[3] = {b1, b2, b3};
  #pragma unroll
  for (int L = 0; L < 3; ++L) {
    const U16* wf = wf_[L];
    const U16* wn = wn_[L];
    const float* bL = bL_[L];
    f32x16 acc[4];
    #pragma unroll
    for (int mt = 0; mt < 4; ++mt)
      #pragma unroll
      for (int j = 0; j < 4; ++j) {
        f32x4 bv = *(const f32x4*)(bL + (mt << 5) + (j << 3) + (h << 2));
        #pragma unroll
        for (int q = 0; q < 4; ++q) acc[mt][4 * j + q] = bv[q];
      }
    HSTEP(0, A0, LDA4(A0, wf, 4));
    HSTEP(1, A1, LDA4(A1, wf, 5));
    HSTEP(2, A2, LDA4(A2, wf, 6));
    HSTEP(3, A3, LDA4(A3, wf, 7));
    if (L < 2) {
      HSTEP(4, A0, LDA4(A0, wn, 0));
      HSTEP(5, A1, LDA4(A1, wn, 1));
      HSTEP(6, A2, LDA4(A2, wn, 2));
      HSTEP(7, A3, LDA4(A3, wn, 3));
    } else {
      HSTEP(4, A0, LDA2(A0, w4f, 0));
      HSTEP(5, A1, LDA2(A1, w4f, 1));
      HSTEP(6, A2, LDA2(A2, w4f, 2));
      HSTEP(7, A3, LDA2(A3, w4f, 3));
    }
    // D -> next-layer B (relu + pack + permlane32_swap)
    #pragma unroll
    for (int mtp = 0; mtp < 4; ++mtp) {
      u32 p[8];
      #pragma unroll
      for (int j2 = 0; j2 < 8; ++j2)
        p[j2] = packf16(fmaxf(acc[mtp][2 * j2], 0.0f), fmaxf(acc[mtp][2 * j2 + 1], 0.0f));
      #pragma unroll
      for (int u = 0; u < 2; ++u)
        #pragma unroll
        for (int w = 0; w < 2; ++w) {
          u32 va = p[w + 4 * u], vb = p[w + 4 * u + 2];
          asm("v_permlane32_swap_b32 %0, %1" : "+v"(va), "+v"(vb));
          Bf[2 * mtp + u][w]     = va;
          Bf[2 * mtp + u][w + 2] = vb;
        }
    }
    __syncthreads();   // keep waves in phase for next layer's weight stream
  }

  // ---- final layer 128 -> 64 (A batches 0..3 already in flight) ----
  f32x16 a4[2];
  #pragma unroll
  for (int mt4 = 0; mt4 < 2; ++mt4)
    #pragma unroll
    for (int r = 0; r < 16; ++r) a4[mt4][r] = 0.0f;
  FSTEP(0, A0, LDA2(A0, w4f, 4));
  FSTEP(1, A1, LDA2(A1, w4f, 5));
  FSTEP(2, A2, LDA2(A2, w4f, 6));
  FSTEP(3, A3, LDA2(A3, w4f, 7));
  FSTEP(4, A0, );
  FSTEP(5, A1, );
  FSTEP(6, A2, );
  FSTEP(7, A3, );

  // ---- area-weighted corner combine across 4-lane groups ----
  float tacc[2][16];
  #pragma unroll
  for (int mt4 = 0; mt4 < 2; ++mt4)
    #pragma unroll
    for (int r = 0; r < 16; ++r) {
      float v = a4[mt4][r] * wgt;
      v += __shfl_xor(v, 1, 64);
      v += __shfl_xor(v, 2, 64);
      tacc[mt4][r] = v;
    }

  if (c == 0) {
    #pragma unroll
    for (int mt4 = 0; mt4 < 2; ++mt4)
      #pragma unroll
      for (int j = 0; j < 4; ++j) {
        int mo = (mt4 << 5) + (j << 3) + (h << 2);
        f32x4 bv = *(const f32x4*)(b4 + mo);
        f32x4 res;
        #pragma unroll
        for (int q = 0; q < 4; ++q) res[q] = tacc[mt4][4 * j + q] + bv[q];
        *(f32x4*)(out + (size_t)gq * 64 + mo) = res;
      }
  }
}

// ---------------------------------------------------------------------------
extern "C" void kernel_launch(void* const* d_in, const int* in_sizes, int n_in,
                              void* d_out, int out_size, void* d_ws, size_t ws_size,
                              hipStream_t stream)
{
  const float* x     = (const float*)d_in[0];
  const float* coord = (const float*)d_in[1];
  const float* cell  = (const float*)d_in[2];
  const float* w0    = (const float*)d_in[3];
  const float* b0    = (const float*)d_in[4];
  const float* w1    = (const float*)d_in[5];
  const float* b1    = (const float*)d_in[6];
  const float* w2    = (const float*)d_in[7];
  const float* b2    = (const float*)d_in[8];
  const float* w3    = (const float*)d_in[9];
  const float* b3    = (const float*)d_in[10];
  const float* w4    = (const float*)d_in[11];
  const float* b4    = (const float*)d_in[12];
  U16* ws = (U16*)d_ws;

  hipLaunchKernelGGL(k_prepw,  dim3(50),  dim3(256), 0, stream, w0, w1, w2, w3, w4, ws);
  hipLaunchKernelGGL(k_stage1, dim3(512), dim3(256), 0, stream,
                     x, ws + W0F_OFF, b0, ws + P_OFF);
  hipLaunchKernelGGL(k_stage2, dim3(512), dim3(256), 0, stream,
                     ws + P_OFF, coord, cell, w0,
                     ws + W1F_OFF, ws + W1F_OFF + 16384, ws + W1F_OFF + 32768, ws + W4F_OFF,
                     b1, b2, b3, b4, (float*)d_out);
}